// Round 2
// baseline (635.304 us; speedup 1.0000x reference)
//
#include <hip/hip_runtime.h>
#include <math.h>

#define NB 16
#define LTOT 327
#define SDIM 256
#define ZD 64
#define NZ (NB * LTOT)

typedef float nt4 __attribute__((ext_vector_type(4)));   // native vec for nontemporal builtins

// region starts (l-space; l=0 collapse token) and lengths
__device__ __constant__ int d_starts[7] = {1, 25, 41, 89, 193, 209, 313};
__device__ __constant__ int d_lens[7]   = {24, 16, 48, 104, 16, 104, 14};

// j-segment boundaries: [token][cdr3][pep][mhc][hv][hj][lv][lj]
__device__ __constant__ int seg_s[8] = {0, 1, 25, 41, 89, 193, 209, 313};
__device__ __constant__ int seg_e[8] = {1, 25, 41, 89, 193, 209, 313, 327};

__device__ __forceinline__ int regid(int x) {
    return (x >= 1) + (x >= 25) + (x >= 41) + (x >= 89) + (x >= 193) + (x >= 209) + (x >= 313);
}

__device__ __forceinline__ int pair_id(int i, int j, int ri, int rj) {
    if ((i == 0) && (j == 0)) return 0;
    if ((i == 0) || (j == 0)) return 1;
    if ((ri == 1) && (rj == 1)) {
        int d = i > j ? i - j : j - i;
        if (d == 1) return 2;
        if (d != 0) return 3;
        return 0;                 // cdr3 diagonal stays 0 (matches jnp.where order)
    }
    if ((ri == 1) || (rj == 1)) return 4;
    if (ri == rj) return 5 + ri - 2;
    int a = (ri < rj ? ri : rj) - 2;
    int c = (ri < rj ? rj : ri) - 2;
    return 11 + a * (11 - a) / 2 + (c - a - 1);   // N_COND=6
}

// -------- pe: (327, 256)  b-invariant positional part, pre-scaled by region_w[k][1]
__global__ __launch_bounds__(256) void pe_kernel(
    const float* __restrict__ posW, const float* __restrict__ posb,
    const float* __restrict__ rw, float* __restrict__ pe_full)
{
    int l = blockIdx.x;            // 0..326; l=0 unused downstream
    int e = threadIdx.x;
    __shared__ float sh_pe[64];

    int k = (l >= 25) + (l >= 41) + (l >= 89) + (l >= 193) + (l >= 209) + (l >= 313);
    int pl = (l == 0) ? 0 : (l - d_starts[k]);
    if (e < 64) {
        float scale = exp2f(-(float)e * (13.287712379549449f / 64.0f)); // 10000^(-e/64)
        float ang = (float)pl * scale;
        sh_pe[e] = (e & 1) ? cosf(ang) : sinf(ang);
    }
    __syncthreads();

    float pe = posb[e];
    const float* pwrow = posW + e * 64;
    #pragma unroll 8
    for (int i2 = 0; i2 < 64; i2++) pe = fmaf(sh_pe[i2], pwrow[i2], pe);
    pe_full[(size_t)l * SDIM + e] = rw[2 * k + 1] * pe;
}

// -------- fused mega-kernel: blocks [0, NZ) do z rows, blocks [NZ, 2*NZ) do s rows
#define TSTRIDE 68   // 64 + 4 pad, keeps 16B alignment

__global__ __launch_bounds__(256) void fused_zs(
    const float* __restrict__ p1W, const float* __restrict__ p1b,
    const float* __restrict__ p2W, const float* __restrict__ p2b,
    const float* __restrict__ s0, const float* __restrict__ s1,
    const float* __restrict__ s2, const float* __restrict__ s3,
    const float* __restrict__ s4, const float* __restrict__ s5,
    const float* __restrict__ s6,
    const float* __restrict__ seqW, const float* __restrict__ seqb,
    const float* __restrict__ ctok, const float* __restrict__ cw,
    const float* __restrict__ rw, const float* __restrict__ pe_full,
    float* __restrict__ out, float* __restrict__ outz)
{
    // union LDS: z-role needs 32*TSTRIDE = 2176 floats; s-role needs 5376 (seqW) + 21
    __shared__ __align__(16) float smem[5408];
    int t = threadIdx.x;
    int blk = blockIdx.x;

    if (blk < NZ) {
        // ---------------- z role: one (b,i) row of (327,64) pure-streaming stores
        float* table = smem;   // 32 rows x TSTRIDE
        for (int idx = t; idx < 32 * 64; idx += 256) {
            int p = idx >> 6, c = idx & 63;
            float v;
            if (c < 32) v = p1W[c * 8 + (p >> 2)] + p1b[c];
            else        v = p2W[(c - 32) * 4 + (p & 3)] + p2b[c - 32];
            table[p * TSTRIDE + c] = v;
        }
        __syncthreads();

        int i = blk % LTOT;
        int ri = regid(i);
        int c8 = t & 7;            // which float4-PAIR of the 8 in a 64-float row
        int jo = t >> 3;           // j offset within a 32-row stripe

        nt4* dst = (nt4*)(outz + (size_t)blk * (LTOT * ZD)) + c8 * 2;

        #pragma unroll
        for (int s = 0; s < 8; s++) {
            int js = seg_s[s], je = seg_e[s];
            if (ri == 1 && s == 1) {
                // cdr3 row x cdr3 segment: p varies with |i-j| in {0(diag),2(adj),3}
                const nt4* r0 = (const nt4*)(table + 0 * TSTRIDE) + c8 * 2;
                const nt4* r2 = (const nt4*)(table + 2 * TSTRIDE) + c8 * 2;
                const nt4* r3 = (const nt4*)(table + 3 * TSTRIDE) + c8 * 2;
                nt4 v0a = r0[0], v0b = r0[1];
                nt4 v2a = r2[0], v2b = r2[1];
                nt4 v3a = r3[0], v3b = r3[1];
                for (int j = js + jo; j < je; j += 32) {
                    int d = i > j ? i - j : j - i;
                    nt4 va = (d == 0) ? v0a : ((d == 1) ? v2a : v3a);
                    nt4 vb = (d == 0) ? v0b : ((d == 1) ? v2b : v3b);
                    __builtin_nontemporal_store(va, dst + j * 16);
                    __builtin_nontemporal_store(vb, dst + j * 16 + 1);
                }
            } else {
                int p = pair_id(i, js, ri, regid(js));   // uniform over the segment
                const nt4* rp = (const nt4*)(table + p * TSTRIDE) + c8 * 2;
                nt4 va = rp[0], vb = rp[1];
                for (int j = js + jo; j < je; j += 32) {
                    __builtin_nontemporal_store(va, dst + j * 16);
                    __builtin_nontemporal_store(vb, dst + j * 16 + 1);
                }
            }
        }
    } else {
        // ---------------- s role: one (b,l) row of (256,) with LDS-staged seqW
        int sb = blk - NZ;         // b*LTOT + l
        int l = sb % LTOT;
        int b = sb / LTOT;
        int e = t;

        if (l == 0) {
            out[(size_t)sb * SDIM + e] = cw[0] * ctok[e];
            return;
        }
        float* sh_w   = smem;          // 256*21 = 5376 floats
        float* sh_seq = smem + 5376;   // 21 floats

        // coalesced stage of seqW (21504 B = 1344 float4, 16B-aligned, exact)
        const float4* wsrc = (const float4*)seqW;
        float4* wdst = (float4*)sh_w;
        for (int idx = t; idx < 1344; idx += 256) wdst[idx] = wsrc[idx];

        int k = (l >= 25) + (l >= 41) + (l >= 89) + (l >= 193) + (l >= 209) + (l >= 313);
        int pl = l - d_starts[k];
        const float* sp;
        switch (k) {
            case 0: sp = s0; break; case 1: sp = s1; break; case 2: sp = s2; break;
            case 3: sp = s3; break; case 4: sp = s4; break; case 5: sp = s5; break;
            default: sp = s6;
        }
        if (e < 21) sh_seq[e] = sp[((size_t)b * d_lens[k] + pl) * 21 + e];
        __syncthreads();

        float se = seqb[e];
        const float* wrow = sh_w + e * 21;   // LDS: stride 21 coprime to 32 banks -> 2-way, free
        #pragma unroll
        for (int d = 0; d < 21; d++) se = fmaf(sh_seq[d], wrow[d], se);

        out[(size_t)sb * SDIM + e] = rw[2 * k] * se + pe_full[(size_t)l * SDIM + e];
    }
}

// -------- fallback path kernels (ws too small for pe_full) --------
__global__ __launch_bounds__(256) void z_kernel(
    const float* __restrict__ p1W, const float* __restrict__ p1b,
    const float* __restrict__ p2W, const float* __restrict__ p2b,
    float* __restrict__ outz)
{
    __shared__ __align__(16) float table[32 * TSTRIDE];
    int t = threadIdx.x;
    for (int idx = t; idx < 32 * 64; idx += 256) {
        int p = idx >> 6, c = idx & 63;
        float v;
        if (c < 32) v = p1W[c * 8 + (p >> 2)] + p1b[c];
        else        v = p2W[(c - 32) * 4 + (p & 3)] + p2b[c - 32];
        table[p * TSTRIDE + c] = v;
    }
    __syncthreads();

    int blk = blockIdx.x;
    int i = blk % LTOT;
    int ri = regid(i);
    int c4 = t & 15;
    int jo = t >> 4;
    float4* dst = (float4*)(outz + (size_t)blk * (LTOT * ZD));

    #pragma unroll
    for (int s = 0; s < 8; s++) {
        int js = seg_s[s], je = seg_e[s];
        if (ri == 1 && s == 1) {
            float4 v0 = *(const float4*)(table + 0 * TSTRIDE + c4 * 4);
            float4 v2 = *(const float4*)(table + 2 * TSTRIDE + c4 * 4);
            float4 v3 = *(const float4*)(table + 3 * TSTRIDE + c4 * 4);
            for (int j = js + jo; j < je; j += 16) {
                int d = i > j ? i - j : j - i;
                float4 v = (d == 0) ? v0 : ((d == 1) ? v2 : v3);
                dst[j * 16 + c4] = v;
            }
        } else {
            int p = pair_id(i, js, ri, regid(js));
            float4 v = *(const float4*)(table + p * TSTRIDE + c4 * 4);
            for (int j = js + jo; j < je; j += 16) {
                dst[j * 16 + c4] = v;
            }
        }
    }
}

__global__ __launch_bounds__(256) void s_kernel(
    const float* __restrict__ s0, const float* __restrict__ s1,
    const float* __restrict__ s2, const float* __restrict__ s3,
    const float* __restrict__ s4, const float* __restrict__ s5,
    const float* __restrict__ s6,
    const float* __restrict__ seqW, const float* __restrict__ seqb,
    const float* __restrict__ posW, const float* __restrict__ posb,
    const float* __restrict__ ctok, const float* __restrict__ cw,
    const float* __restrict__ rw,
    float* __restrict__ out)
{
    int blk = blockIdx.x;
    int l = blk % LTOT;
    int b = blk / LTOT;
    int e = threadIdx.x;
    if (l == 0) { out[(size_t)blk * SDIM + e] = cw[0] * ctok[e]; return; }
    __shared__ float sh_seq[21];
    __shared__ float sh_pe[64];
    int k = (l >= 25) + (l >= 41) + (l >= 89) + (l >= 193) + (l >= 209) + (l >= 313);
    int pl = l - d_starts[k];
    const float* sp;
    switch (k) {
        case 0: sp = s0; break; case 1: sp = s1; break; case 2: sp = s2; break;
        case 3: sp = s3; break; case 4: sp = s4; break; case 5: sp = s5; break;
        default: sp = s6;
    }
    if (e < 21) sh_seq[e] = sp[((size_t)b * d_lens[k] + pl) * 21 + e];
    if (e < 64) {
        float scale = exp2f(-(float)e * (13.287712379549449f / 64.0f));
        float ang = (float)pl * scale;
        sh_pe[e] = (e & 1) ? cosf(ang) : sinf(ang);
    }
    __syncthreads();
    float se = seqb[e];
    const float* wrow = seqW + e * 21;
    #pragma unroll
    for (int d = 0; d < 21; d++) se = fmaf(sh_seq[d], wrow[d], se);
    float pe = posb[e];
    const float* pwrow = posW + e * 64;
    #pragma unroll 8
    for (int i2 = 0; i2 < 64; i2++) pe = fmaf(sh_pe[i2], pwrow[i2], pe);
    out[(size_t)blk * SDIM + e] = rw[2 * k] * se + rw[2 * k + 1] * pe;
}

extern "C" void kernel_launch(void* const* d_in, const int* in_sizes, int n_in,
                              void* d_out, int out_size, void* d_ws, size_t ws_size,
                              hipStream_t stream) {
    const float* seq0 = (const float*)d_in[0];
    const float* seq1 = (const float*)d_in[1];
    const float* seq2 = (const float*)d_in[2];
    const float* seq3 = (const float*)d_in[3];
    const float* seq4 = (const float*)d_in[4];
    const float* seq5 = (const float*)d_in[5];
    const float* seq6 = (const float*)d_in[6];
    const float* seqW = (const float*)d_in[7];
    const float* seqb = (const float*)d_in[8];
    const float* posW = (const float*)d_in[9];
    const float* posb = (const float*)d_in[10];
    const float* p1W  = (const float*)d_in[11];
    const float* p1b  = (const float*)d_in[12];
    const float* p2W  = (const float*)d_in[13];
    const float* p2b  = (const float*)d_in[14];
    const float* ctok = (const float*)d_in[15];
    const float* cw   = (const float*)d_in[16];
    const float* rw   = (const float*)d_in[17];

    float* out = (float*)d_out;
    float* outz = out + (size_t)NB * LTOT * SDIM;

    if (ws_size >= (size_t)LTOT * SDIM * sizeof(float)) {
        float* pe_full = (float*)d_ws;
        // tiny prologue (~2 us): b-invariant positional matvec
        pe_kernel<<<LTOT, 256, 0, stream>>>(posW, posb, rw, pe_full);
        // one launch: z blocks first (own the store stream), s blocks backfill
        fused_zs<<<2 * NZ, 256, 0, stream>>>(p1W, p1b, p2W, p2b,
                                             seq0, seq1, seq2, seq3, seq4, seq5, seq6,
                                             seqW, seqb, ctok, cw, rw, pe_full,
                                             out, outz);
    } else {
        z_kernel<<<NZ, 256, 0, stream>>>(p1W, p1b, p2W, p2b, outz);
        s_kernel<<<NZ, 256, 0, stream>>>(seq0, seq1, seq2, seq3, seq4, seq5, seq6,
                                         seqW, seqb, posW, posb, ctok, cw, rw, out);
    }
}

// Round 3
// 510.294 us; speedup vs baseline: 1.2450x; 1.2450x over previous
//
#include <hip/hip_runtime.h>
#include <math.h>

#define NB 16
#define LTOT 327
#define SDIM 256
#define ZD 64
#define NZ (NB * LTOT)
#define TSTRIDE 68   // 64 + 4 pad, keeps 16B alignment

// region starts (l-space; l=0 collapse token) and lengths
__device__ __constant__ int d_starts[7] = {1, 25, 41, 89, 193, 209, 313};
__device__ __constant__ int d_lens[7]   = {24, 16, 48, 104, 16, 104, 14};

// j-segment boundaries: [token][cdr3][pep][mhc][hv][hj][lv][lj]
__device__ __constant__ int seg_s[8] = {0, 1, 25, 41, 89, 193, 209, 313};
__device__ __constant__ int seg_e[8] = {1, 25, 41, 89, 193, 209, 313, 327};

__device__ __forceinline__ int regid(int x) {
    return (x >= 1) + (x >= 25) + (x >= 41) + (x >= 89) + (x >= 193) + (x >= 209) + (x >= 313);
}

__device__ __forceinline__ int pair_id(int i, int j, int ri, int rj) {
    if ((i == 0) && (j == 0)) return 0;
    if ((i == 0) || (j == 0)) return 1;
    if ((ri == 1) && (rj == 1)) {
        int d = i > j ? i - j : j - i;
        if (d == 1) return 2;
        if (d != 0) return 3;
        return 0;                 // cdr3 diagonal stays 0 (matches jnp.where order)
    }
    if ((ri == 1) || (rj == 1)) return 4;
    if (ri == rj) return 5 + ri - 2;
    int a = (ri < rj ? ri : rj) - 2;
    int c = (ri < rj ? rj : ri) - 2;
    return 11 + a * (11 - a) / 2 + (c - a - 1);   // N_COND=6
}

// -------- single fused kernel --------
// grid = 2*NZ. Even blocks: one (b,i) z-row (pure streaming stores, BW-bound).
// Odd blocks: one (b,l) s-row (L1-gather + VALU, latency-bound) — interleaved so
// the s work hides under z's write stream instead of running serially after it.
__global__ __launch_bounds__(256) void fused_all(
    const float* __restrict__ p1W, const float* __restrict__ p1b,
    const float* __restrict__ p2W, const float* __restrict__ p2b,
    const float* __restrict__ s0, const float* __restrict__ s1,
    const float* __restrict__ s2, const float* __restrict__ s3,
    const float* __restrict__ s4, const float* __restrict__ s5,
    const float* __restrict__ s6,
    const float* __restrict__ seqW, const float* __restrict__ seqb,
    const float* __restrict__ posW, const float* __restrict__ posb,
    const float* __restrict__ ctok, const float* __restrict__ cw,
    const float* __restrict__ rw,
    float* __restrict__ out, float* __restrict__ outz)
{
    __shared__ __align__(16) float smem[32 * TSTRIDE];   // 8704 B (union of both roles)
    int t = threadIdx.x;
    int blk0 = blockIdx.x;

    if ((blk0 & 1) == 0) {
        // ---------------- z role: one (b,i) row of (327,64) pure-streaming stores
        int blk = blk0 >> 1;       // b*LTOT + i
        float* table = smem;       // 32 rows x TSTRIDE
        for (int idx = t; idx < 32 * 64; idx += 256) {
            int p = idx >> 6, c = idx & 63;
            float v;
            if (c < 32) v = p1W[c * 8 + (p >> 2)] + p1b[c];
            else        v = p2W[(c - 32) * 4 + (p & 3)] + p2b[c - 32];
            table[p * TSTRIDE + c] = v;
        }
        __syncthreads();

        int i = blk % LTOT;
        int ri = regid(i);
        int c4 = t & 15;           // which float4 of the 16 in a 64-float row
        int jo = t >> 4;           // j offset within a 16-row stripe

        // one wave store-instruction = 4 consecutive 256B rows = 1KB contiguous
        float4* dst = (float4*)(outz + (size_t)blk * (LTOT * ZD));

        #pragma unroll
        for (int s = 0; s < 8; s++) {
            int js = seg_s[s], je = seg_e[s];
            if (ri == 1 && s == 1) {
                // cdr3 row x cdr3 segment: p varies with |i-j| in {0(diag),2(adj),3}
                float4 v0 = *(const float4*)(table + 0 * TSTRIDE + c4 * 4);
                float4 v2 = *(const float4*)(table + 2 * TSTRIDE + c4 * 4);
                float4 v3 = *(const float4*)(table + 3 * TSTRIDE + c4 * 4);
                for (int j = js + jo; j < je; j += 16) {
                    int d = i > j ? i - j : j - i;
                    float4 v = (d == 0) ? v0 : ((d == 1) ? v2 : v3);
                    dst[j * 16 + c4] = v;
                }
            } else {
                int p = pair_id(i, js, ri, regid(js));   // uniform over the segment
                float4 v = *(const float4*)(table + p * TSTRIDE + c4 * 4);
                for (int j = js + jo; j < je; j += 16) {
                    dst[j * 16 + c4] = v;                // pure streaming store
                }
            }
        }
    } else {
        // ---------------- s role: one (b,l) row of (256,), positional part inline
        int sb = blk0 >> 1;        // b*LTOT + l
        int l = sb % LTOT;
        int b = sb / LTOT;
        int e = t;

        if (l == 0) {
            out[(size_t)sb * SDIM + e] = cw[0] * ctok[e];
            return;
        }
        float* sh_seq = smem;        // 21 floats
        float* sh_pe  = smem + 32;   // 64 floats

        int k = (l >= 25) + (l >= 41) + (l >= 89) + (l >= 193) + (l >= 209) + (l >= 313);
        int pl = l - d_starts[k];
        const float* sp;
        switch (k) {
            case 0: sp = s0; break; case 1: sp = s1; break; case 2: sp = s2; break;
            case 3: sp = s3; break; case 4: sp = s4; break; case 5: sp = s5; break;
            default: sp = s6;
        }
        if (e < 21) sh_seq[e] = sp[((size_t)b * d_lens[k] + pl) * 21 + e];
        if (e < 64) {
            float scale = exp2f(-(float)e * (13.287712379549449f / 64.0f)); // 10000^(-e/64)
            float ang = (float)pl * scale;
            sh_pe[e] = (e & 1) ? cosf(ang) : sinf(ang);
        }
        __syncthreads();

        float se = seqb[e];
        const float* wrow = seqW + e * 21;
        #pragma unroll
        for (int d = 0; d < 21; d++) se = fmaf(sh_seq[d], wrow[d], se);

        float pe = posb[e];
        const float* pwrow = posW + e * 64;
        #pragma unroll 8
        for (int i2 = 0; i2 < 64; i2++) pe = fmaf(sh_pe[i2], pwrow[i2], pe);

        out[(size_t)sb * SDIM + e] = rw[2 * k] * se + rw[2 * k + 1] * pe;
    }
}

extern "C" void kernel_launch(void* const* d_in, const int* in_sizes, int n_in,
                              void* d_out, int out_size, void* d_ws, size_t ws_size,
                              hipStream_t stream) {
    const float* seq0 = (const float*)d_in[0];
    const float* seq1 = (const float*)d_in[1];
    const float* seq2 = (const float*)d_in[2];
    const float* seq3 = (const float*)d_in[3];
    const float* seq4 = (const float*)d_in[4];
    const float* seq5 = (const float*)d_in[5];
    const float* seq6 = (const float*)d_in[6];
    const float* seqW = (const float*)d_in[7];
    const float* seqb = (const float*)d_in[8];
    const float* posW = (const float*)d_in[9];
    const float* posb = (const float*)d_in[10];
    const float* p1W  = (const float*)d_in[11];
    const float* p1b  = (const float*)d_in[12];
    const float* p2W  = (const float*)d_in[13];
    const float* p2b  = (const float*)d_in[14];
    const float* ctok = (const float*)d_in[15];
    const float* cw   = (const float*)d_in[16];
    const float* rw   = (const float*)d_in[17];

    float* out = (float*)d_out;
    float* outz = out + (size_t)NB * LTOT * SDIM;

    // one launch: z blocks (even) interleaved with s blocks (odd)
    fused_all<<<2 * NZ, 256, 0, stream>>>(p1W, p1b, p2W, p2b,
                                          seq0, seq1, seq2, seq3, seq4, seq5, seq6,
                                          seqW, seqb, posW, posb, ctok, cw, rw,
                                          out, outz);
}

// Round 4
// 505.991 us; speedup vs baseline: 1.2556x; 1.0085x over previous
//
#include <hip/hip_runtime.h>
#include <math.h>

#define NB 16
#define LTOT 327
#define SDIM 256
#define ZD 64
#define NZ (NB * LTOT)
#define TSTRIDE 68   // 64 + 4 pad, keeps 16B alignment

typedef float nt4 __attribute__((ext_vector_type(4)));   // native vec for nontemporal builtins

// region starts (l-space; l=0 collapse token) and lengths
__device__ __constant__ int d_starts[7] = {1, 25, 41, 89, 193, 209, 313};
__device__ __constant__ int d_lens[7]   = {24, 16, 48, 104, 16, 104, 14};

// j-segment boundaries: [token][cdr3][pep][mhc][hv][hj][lv][lj]
__device__ __constant__ int seg_s[8] = {0, 1, 25, 41, 89, 193, 209, 313};
__device__ __constant__ int seg_e[8] = {1, 25, 41, 89, 193, 209, 313, 327};

__device__ __forceinline__ int regid(int x) {
    return (x >= 1) + (x >= 25) + (x >= 41) + (x >= 89) + (x >= 193) + (x >= 209) + (x >= 313);
}

__device__ __forceinline__ int pair_id(int i, int j, int ri, int rj) {
    if ((i == 0) && (j == 0)) return 0;
    if ((i == 0) || (j == 0)) return 1;
    if ((ri == 1) && (rj == 1)) {
        int d = i > j ? i - j : j - i;
        if (d == 1) return 2;
        if (d != 0) return 3;
        return 0;                 // cdr3 diagonal stays 0 (matches jnp.where order)
    }
    if ((ri == 1) || (rj == 1)) return 4;
    if (ri == rj) return 5 + ri - 2;
    int a = (ri < rj ? ri : rj) - 2;
    int c = (ri < rj ? rj : ri) - 2;
    return 11 + a * (11 - a) / 2 + (c - a - 1);   // N_COND=6
}

// -------- single fused kernel --------
// grid = 2*NZ. Even blocks: one (b,i) z-row (nontemporal streaming stores, BW-bound).
// Odd blocks: one (b,l) s-row (L1-gather + VALU, latency-bound).
__global__ __launch_bounds__(256) void fused_all(
    const float* __restrict__ p1W, const float* __restrict__ p1b,
    const float* __restrict__ p2W, const float* __restrict__ p2b,
    const float* __restrict__ s0, const float* __restrict__ s1,
    const float* __restrict__ s2, const float* __restrict__ s3,
    const float* __restrict__ s4, const float* __restrict__ s5,
    const float* __restrict__ s6,
    const float* __restrict__ seqW, const float* __restrict__ seqb,
    const float* __restrict__ posW, const float* __restrict__ posb,
    const float* __restrict__ ctok, const float* __restrict__ cw,
    const float* __restrict__ rw,
    float* __restrict__ out, float* __restrict__ outz)
{
    __shared__ __align__(16) float smem[32 * TSTRIDE];   // 8704 B (union of both roles)
    int t = threadIdx.x;
    int blk0 = blockIdx.x;

    if ((blk0 & 1) == 0) {
        // ---------------- z role: one (b,i) row of (327,64) streaming stores
        int blk = blk0 >> 1;       // b*LTOT + i
        float* table = smem;       // 32 rows x TSTRIDE
        for (int idx = t; idx < 32 * 64; idx += 256) {
            int p = idx >> 6, c = idx & 63;
            float v;
            if (c < 32) v = p1W[c * 8 + (p >> 2)] + p1b[c];
            else        v = p2W[(c - 32) * 4 + (p & 3)] + p2b[c - 32];
            table[p * TSTRIDE + c] = v;
        }
        __syncthreads();

        int i = blk % LTOT;
        int ri = regid(i);
        int c4 = t & 15;           // which float4 of the 16 in a 64-float row
        int jo = t >> 4;           // j offset within a 16-row stripe

        // one wave store-instruction = 4 consecutive 256B rows = 1KB contiguous.
        // NT: write-once 438MB stream — don't allocate in L2/LLC.
        nt4* dst = (nt4*)(outz + (size_t)blk * (LTOT * ZD));

        #pragma unroll
        for (int s = 0; s < 8; s++) {
            int js = seg_s[s], je = seg_e[s];
            if (ri == 1 && s == 1) {
                // cdr3 row x cdr3 segment: p varies with |i-j| in {0(diag),2(adj),3}
                nt4 v0 = *(const nt4*)(table + 0 * TSTRIDE + c4 * 4);
                nt4 v2 = *(const nt4*)(table + 2 * TSTRIDE + c4 * 4);
                nt4 v3 = *(const nt4*)(table + 3 * TSTRIDE + c4 * 4);
                for (int j = js + jo; j < je; j += 16) {
                    int d = i > j ? i - j : j - i;
                    nt4 v = (d == 0) ? v0 : ((d == 1) ? v2 : v3);
                    __builtin_nontemporal_store(v, dst + j * 16 + c4);
                }
            } else {
                int p = pair_id(i, js, ri, regid(js));   // uniform over the segment
                nt4 v = *(const nt4*)(table + p * TSTRIDE + c4 * 4);
                for (int j = js + jo; j < je; j += 16) {
                    __builtin_nontemporal_store(v, dst + j * 16 + c4);
                }
            }
        }
    } else {
        // ---------------- s role: one (b,l) row of (256,), positional part inline
        int sb = blk0 >> 1;        // b*LTOT + l
        int l = sb % LTOT;
        int b = sb / LTOT;
        int e = t;

        if (l == 0) {
            out[(size_t)sb * SDIM + e] = cw[0] * ctok[e];
            return;
        }
        float* sh_seq = smem;        // 21 floats
        float* sh_pe  = smem + 32;   // 64 floats

        int k = (l >= 25) + (l >= 41) + (l >= 89) + (l >= 193) + (l >= 209) + (l >= 313);
        int pl = l - d_starts[k];
        const float* sp;
        switch (k) {
            case 0: sp = s0; break; case 1: sp = s1; break; case 2: sp = s2; break;
            case 3: sp = s3; break; case 4: sp = s4; break; case 5: sp = s5; break;
            default: sp = s6;
        }
        if (e < 21) sh_seq[e] = sp[((size_t)b * d_lens[k] + pl) * 21 + e];
        if (e < 64) {
            float scale = exp2f(-(float)e * (13.287712379549449f / 64.0f)); // 10000^(-e/64)
            float ang = (float)pl * scale;
            sh_pe[e] = (e & 1) ? cosf(ang) : sinf(ang);
        }
        __syncthreads();

        float se = seqb[e];
        const float* wrow = seqW + e * 21;
        #pragma unroll
        for (int d = 0; d < 21; d++) se = fmaf(sh_seq[d], wrow[d], se);

        float pe = posb[e];
        const float* pwrow = posW + e * 64;
        #pragma unroll 8
        for (int i2 = 0; i2 < 64; i2++) pe = fmaf(sh_pe[i2], pwrow[i2], pe);

        out[(size_t)sb * SDIM + e] = rw[2 * k] * se + rw[2 * k + 1] * pe;
    }
}

extern "C" void kernel_launch(void* const* d_in, const int* in_sizes, int n_in,
                              void* d_out, int out_size, void* d_ws, size_t ws_size,
                              hipStream_t stream) {
    const float* seq0 = (const float*)d_in[0];
    const float* seq1 = (const float*)d_in[1];
    const float* seq2 = (const float*)d_in[2];
    const float* seq3 = (const float*)d_in[3];
    const float* seq4 = (const float*)d_in[4];
    const float* seq5 = (const float*)d_in[5];
    const float* seq6 = (const float*)d_in[6];
    const float* seqW = (const float*)d_in[7];
    const float* seqb = (const float*)d_in[8];
    const float* posW = (const float*)d_in[9];
    const float* posb = (const float*)d_in[10];
    const float* p1W  = (const float*)d_in[11];
    const float* p1b  = (const float*)d_in[12];
    const float* p2W  = (const float*)d_in[13];
    const float* p2b  = (const float*)d_in[14];
    const float* ctok = (const float*)d_in[15];
    const float* cw   = (const float*)d_in[16];
    const float* rw   = (const float*)d_in[17];

    float* out = (float*)d_out;
    float* outz = out + (size_t)NB * LTOT * SDIM;

    // one launch: z blocks (even) interleaved with s blocks (odd)
    fused_all<<<2 * NZ, 256, 0, stream>>>(p1W, p1b, p2W, p2b,
                                          seq0, seq1, seq2, seq3, seq4, seq5, seq6,
                                          seqW, seqb, posW, posb, ctok, cw, rw,
                                          out, outz);
}